// Round 5
// baseline (6816.737 us; speedup 1.0000x reference)
//
#include <hip/hip_runtime.h>
#include <hip/hip_bf16.h>
#include <hip/hip_fp16.h>

#define FDIM 128
#define CF 16   // features per chunk: 32B fp16 rows, 3.2MB chunk -> L2-resident

typedef float f4 __attribute__((ext_vector_type(4)));

// ---------- degree / dinv ----------

__global__ void degree_kernel(const int* __restrict__ col, int* __restrict__ deg, int E) {
    int e = blockIdx.x * blockDim.x + threadIdx.x;
    if (e < E) atomicAdd(&deg[col[e]], 1);
}

__global__ void dinv_kernel(const int* __restrict__ deg, float* __restrict__ dinv, int N) {
    int i = blockIdx.x * blockDim.x + threadIdx.x;
    if (i < N) {
        int d = deg[i];
        dinv[i] = (d > 0) ? rsqrtf((float)d) : 0.0f;
    }
}

// ---------- exclusive scan of deg -> rowptr ----------

__global__ void scan_blocks_kernel(const int* __restrict__ deg, int* __restrict__ rowptr,
                                   int* __restrict__ bsum, int N) {
    __shared__ int s[256];
    int t = threadIdx.x;
    int i = blockIdx.x * 256 + t;
    int v = (i < N) ? deg[i] : 0;
    s[t] = v;
    __syncthreads();
    for (int off = 1; off < 256; off <<= 1) {
        int add = (t >= off) ? s[t - off] : 0;
        __syncthreads();
        s[t] += add;
        __syncthreads();
    }
    if (i < N) rowptr[i] = s[t] - v;
    if (t == 255) bsum[blockIdx.x] = s[255];
}

__global__ void scan_bsums_kernel(int* __restrict__ bsum, int* __restrict__ boff, int nb) {
    __shared__ int s[512];
    int t = threadIdx.x;
    int v = (t < nb) ? bsum[t] : 0;
    s[t] = v;
    __syncthreads();
    for (int off = 1; off < 512; off <<= 1) {
        int add = (t >= off) ? s[t - off] : 0;
        __syncthreads();
        s[t] += add;
        __syncthreads();
    }
    if (t < nb) boff[t] = s[t] - v;
}

__global__ void add_offsets_kernel(int* __restrict__ rowptr, int* __restrict__ cursor,
                                   const int* __restrict__ boff, int N, int E) {
    int i = blockIdx.x * blockDim.x + threadIdx.x;
    if (i < N) {
        int v = rowptr[i] + boff[i >> 8];
        rowptr[i] = v;
        cursor[i] = v;
    }
    if (i == 0) rowptr[N] = E;
}

// ---------- edge placement: CSR by destination, index only ----------

__global__ void place_kernel(const int* __restrict__ row, const int* __restrict__ col,
                             int* __restrict__ cursor, int* __restrict__ eidx, int E) {
    int e = blockIdx.x * blockDim.x + threadIdx.x;
    if (e < E) {
        int c = col[e];
        int pos = atomicAdd(&cursor[c], 1);
        eidx[pos] = row[e];
    }
}

// ---------- out = mf[0] * x ; hx = fp16(dinv[n] * x) in CHUNKED layout ----------

__global__ void init_out_kernel(const float4* __restrict__ x, const float* __restrict__ mf,
                                const float* __restrict__ dinv,
                                float4* __restrict__ out, __half* __restrict__ hx,
                                int N, long n8) {
    long i = (long)blockIdx.x * blockDim.x + threadIdx.x;
    if (i < n8) {
        float w = mf[0];
        float4 a = x[2 * i];
        float4 b = x[2 * i + 1];
        out[2 * i]     = make_float4(w * a.x, w * a.y, w * a.z, w * a.w);
        out[2 * i + 1] = make_float4(w * b.x, w * b.y, w * b.z, w * b.w);
        long n  = i >> 4;            // node (16 threads per node)
        int  f0 = (int)(i & 15) * 8; // first feature
        float dv = dinv[n];
        __half2 h[4];
        h[0] = __floats2half2_rn(dv * a.x, dv * a.y);
        h[1] = __floats2half2_rn(dv * a.z, dv * a.w);
        h[2] = __floats2half2_rn(dv * b.x, dv * b.y);
        h[3] = __floats2half2_rn(dv * b.z, dv * b.w);
        long haddr = ((long)(f0 >> 4) * N + n) * CF + (f0 & 8);
        *(f4*)(hx + haddr) = *(const f4*)h;
    }
}

// ---------- fused gather prop: feature-chunked, XCD-pinned, no reduction ----------
// chunk c = blockIdx.x & 7 -> XCD c: gathers hit this XCD's L2-resident 3.2MB
// shadow chunk. EVERYTHING ELSE (eidx, rowptr, dinv, fp32 streams) is
// non-temporal so it cannot evict the chunk (round-3/4 A-B: cacheable eidx
// stream -> 1.12GB fetch; nt streams -> 275MB). eidx line reuse over the
// 16-iter window is served by L1.
// Wave = 32 consecutive dsts x 2 feature-lanes; 1KB gather per instruction.

__global__ __launch_bounds__(256) void gather_prop_kernel(
        const int* __restrict__ eidx, const int* __restrict__ rowptr,
        const float* __restrict__ dinv,
        const __half* __restrict__ src, const float* __restrict__ prev2,
        float* __restrict__ tgt, __half* __restrict__ tgth, float* __restrict__ out,
        const float* __restrict__ mf, const float* __restrict__ lap,
        int i_coef, float scale, float beta, int N) {
    const int c    = blockIdx.x & 7;           // chunk -> XCD
    const int wave = threadIdx.x >> 6;
    const int lane = threadIdx.x & 63;
    const int dloc = lane >> 1;                // dst within wave 0..31
    const int fg   = lane & 1;                 // feature half: 8 fp16 = 16B
    const long cN  = (long)c * N;

    int d = (blockIdx.x >> 3) * 128 + wave * 32 + dloc;
    bool valid = d < N;
    int begin = 0, nit = 0;
    if (valid) {
        begin = __builtin_nontemporal_load(rowptr + d);
        nit   = __builtin_nontemporal_load(rowptr + d + 1) - begin;
    }
    int maxit = nit;
    #pragma unroll
    for (int m = 2; m <= 32; m <<= 1)
        maxit = max(maxit, __shfl_xor(maxit, m, 64));

    float acc[8];
    #pragma unroll
    for (int j = 0; j < 8; ++j) acc[j] = 0.f;

    const __half* srcc = src + (cN << 4) + (fg << 3);

    #pragma unroll 4
    for (int k = 0; k < maxit; ++k) {
        int idx = 0;
        float wsel = 0.f;
        if (k < nit) {
            idx = __builtin_nontemporal_load(eidx + begin + k);  // L1-reused, L2-nt
            wsel = 1.f;
        }
        f4 raw = *(const f4*)(srcc + ((long)idx << 4));
        const __half2* h = (const __half2*)&raw;
        float2 f0 = __half22float2(h[0]);
        float2 f1 = __half22float2(h[1]);
        float2 f2 = __half22float2(h[2]);
        float2 f3 = __half22float2(h[3]);
        acc[0] += wsel * f0.x; acc[1] += wsel * f0.y;
        acc[2] += wsel * f1.x; acc[3] += wsel * f1.y;
        acc[4] += wsel * f2.x; acc[5] += wsel * f2.y;
        acc[6] += wsel * f3.x; acc[7] += wsel * f3.y;
    }

    if (!valid) return;

    float dv   = __builtin_nontemporal_load(dinv + d);
    float sdv  = scale * dv;
    float coef = mf[i_coef] * lap[i_coef - 1];
    long  o    = ((long)d << 7) + (c << 4) + (fg << 3);  // fp32 linear elem offset

    float r[8];
    if (beta != 0.f) {
        f4 p0 = __builtin_nontemporal_load((const f4*)(prev2 + o));
        f4 p1 = __builtin_nontemporal_load((const f4*)(prev2 + o) + 1);
        r[0] = sdv * acc[0] + beta * p0.x;
        r[1] = sdv * acc[1] + beta * p0.y;
        r[2] = sdv * acc[2] + beta * p0.z;
        r[3] = sdv * acc[3] + beta * p0.w;
        r[4] = sdv * acc[4] + beta * p1.x;
        r[5] = sdv * acc[5] + beta * p1.y;
        r[6] = sdv * acc[6] + beta * p1.z;
        r[7] = sdv * acc[7] + beta * p1.w;
    } else {
        #pragma unroll
        for (int j = 0; j < 8; ++j) r[j] = sdv * acc[j];
    }
    f4 t0 = {r[0], r[1], r[2], r[3]};
    f4 t1 = {r[4], r[5], r[6], r[7]};
    __builtin_nontemporal_store(t0, (f4*)(tgt + o));
    __builtin_nontemporal_store(t1, (f4*)(tgt + o) + 1);
    if (tgth) {
        // chunked dinv-scaled shadow: cacheable -> stays in this XCD's L2
        __half2 hh[4];
        hh[0] = __floats2half2_rn(dv * r[0], dv * r[1]);
        hh[1] = __floats2half2_rn(dv * r[2], dv * r[3]);
        hh[2] = __floats2half2_rn(dv * r[4], dv * r[5]);
        hh[3] = __floats2half2_rn(dv * r[6], dv * r[7]);
        *(f4*)(tgth + ((cN + d) << 4) + (fg << 3)) = *(const f4*)hh;
    }
    f4 o0 = __builtin_nontemporal_load((const f4*)(out + o));
    f4 o1 = __builtin_nontemporal_load((const f4*)(out + o) + 1);
    o0.x += coef * r[0]; o0.y += coef * r[1]; o0.z += coef * r[2]; o0.w += coef * r[3];
    o1.x += coef * r[4]; o1.y += coef * r[5]; o1.z += coef * r[6]; o1.w += coef * r[7];
    __builtin_nontemporal_store(o0, (f4*)(out + o));
    __builtin_nontemporal_store(o1, (f4*)(out + o) + 1);
}

extern "C" void kernel_launch(void* const* d_in, const int* in_sizes, int n_in,
                              void* d_out, int out_size, void* d_ws, size_t ws_size,
                              hipStream_t stream) {
    const float* x   = (const float*)d_in[0];
    const float* mf  = (const float*)d_in[1];
    const float* lap = (const float*)d_in[2];
    const int*   ei  = (const int*)d_in[3];
    float* out = (float*)d_out;

    const int  K  = in_sizes[1] - 1;          // 10
    const long NF = (long)in_sizes[0];        // N*F
    const int  N  = (int)(NF / FDIM);         // 100000
    const int  E  = in_sizes[3] / 2;          // 3200000
    const int* row = ei;
    const int* col = ei + E;

    // workspace layout (~170 MB)
    char* wp = (char*)d_ws;
    float*  bufA   = (float*)wp;  wp += NF * sizeof(float);
    float*  bufB   = (float*)wp;  wp += NF * sizeof(float);
    __half* hbufA  = (__half*)wp; wp += NF * sizeof(__half);
    __half* hbufB  = (__half*)wp; wp += NF * sizeof(__half);
    int*    eidx   = (int*)wp;    wp += (size_t)E * sizeof(int);
    int*    rowptr = (int*)wp;    wp += (size_t)(N + 1) * sizeof(int);
    int*    cursor = (int*)wp;    wp += (size_t)N * sizeof(int);
    int*    deg    = (int*)wp;    wp += (size_t)N * sizeof(int);
    float*  dinv   = (float*)wp;  wp += (size_t)N * sizeof(float);
    int*    bsum   = (int*)wp;    wp += 512 * sizeof(int);
    int*    boff   = (int*)wp;    wp += 512 * sizeof(int);

    const int BT = 256;
    const long n8 = NF / 8;
    const int n8_blocks = (int)((n8 + BT - 1) / BT);
    const int e_blocks  = (E + BT - 1) / BT;
    const int n_blocks  = (N + BT - 1) / BT;

    // CSR build
    hipMemsetAsync(deg, 0, (size_t)N * sizeof(int), stream);
    degree_kernel<<<e_blocks, BT, 0, stream>>>(col, deg, E);
    dinv_kernel<<<n_blocks, BT, 0, stream>>>(deg, dinv, N);
    scan_blocks_kernel<<<n_blocks, BT, 0, stream>>>(deg, rowptr, bsum, N);
    scan_bsums_kernel<<<1, 512, 0, stream>>>(bsum, boff, n_blocks);
    add_offsets_kernel<<<n_blocks, BT, 0, stream>>>(rowptr, cursor, boff, N, E);
    place_kernel<<<e_blocks, BT, 0, stream>>>(row, col, cursor, eidx, E);

    // out = mf0 * x ; hbufB = fp16(dinv*x) chunked  (hbufB free until i=2)
    init_out_kernel<<<n8_blocks, BT, 0, stream>>>((const float4*)x, mf, dinv,
                                                  (float4*)out, hbufB, N, n8);

    // grid: 8 chunks x (128 dsts per block); chunk = bid & 7 -> XCD pin
    const int g_blocks = 8 * ((N + 127) / 128);

    // P1 = prop(x) -> bufA (+hbufA) ; out += c1*P1   (gathers chunked fp16 dinv*x)
    gather_prop_kernel<<<g_blocks, BT, 0, stream>>>(eidx, rowptr, dinv, hbufB, x,
                                                    bufA, hbufA, out, mf, lap,
                                                    1, 1.0f, 0.0f, N);
    // P_i = 2*prop(P_{i-1}) - P_{i-2} ; out += c_i*P_i   (gathers fp16 shadow)
    for (int i = 2; i <= K; ++i) {
        const __half* srch  = (i % 2 == 0) ? hbufA : hbufB;  // fp16(dinv*P_{i-1})
        float*        tgt   = (i % 2 == 0) ? bufB : bufA;    // P_i (overwrites P_{i-2})
        __half*       tgth  = (i % 2 == 0) ? hbufB : hbufA;
        const float*  prev2 = (i == 2) ? x : (const float*)tgt;
        if (i == K) tgth = nullptr;  // last shadow never gathered
        gather_prop_kernel<<<g_blocks, BT, 0, stream>>>(eidx, rowptr, dinv, srch, prev2,
                                                        tgt, tgth, out, mf, lap,
                                                        i, 2.0f, -1.0f, N);
    }
}

// Round 6
// 2892.744 us; speedup vs baseline: 2.3565x; 2.3565x over previous
//
#include <hip/hip_runtime.h>
#include <hip/hip_bf16.h>
#include <hip/hip_fp16.h>

#define FDIM 128
#define CF 16       // features per chunk: 32B fp16 rows, 3.2MB chunk -> L2-resident
#define DPB 128     // dsts per block
#define TILE_E 6144 // LDS-staged edge indices per tile (24KB); expected window 4096+-64

typedef float f4 __attribute__((ext_vector_type(4)));

// ---------- degree / dinv ----------

__global__ void degree_kernel(const int* __restrict__ col, int* __restrict__ deg, int E) {
    int e = blockIdx.x * blockDim.x + threadIdx.x;
    if (e < E) atomicAdd(&deg[col[e]], 1);
}

__global__ void dinv_kernel(const int* __restrict__ deg, float* __restrict__ dinv, int N) {
    int i = blockIdx.x * blockDim.x + threadIdx.x;
    if (i < N) {
        int d = deg[i];
        dinv[i] = (d > 0) ? rsqrtf((float)d) : 0.0f;
    }
}

// ---------- exclusive scan of deg -> rowptr ----------

__global__ void scan_blocks_kernel(const int* __restrict__ deg, int* __restrict__ rowptr,
                                   int* __restrict__ bsum, int N) {
    __shared__ int s[256];
    int t = threadIdx.x;
    int i = blockIdx.x * 256 + t;
    int v = (i < N) ? deg[i] : 0;
    s[t] = v;
    __syncthreads();
    for (int off = 1; off < 256; off <<= 1) {
        int add = (t >= off) ? s[t - off] : 0;
        __syncthreads();
        s[t] += add;
        __syncthreads();
    }
    if (i < N) rowptr[i] = s[t] - v;
    if (t == 255) bsum[blockIdx.x] = s[255];
}

__global__ void scan_bsums_kernel(int* __restrict__ bsum, int* __restrict__ boff, int nb) {
    __shared__ int s[512];
    int t = threadIdx.x;
    int v = (t < nb) ? bsum[t] : 0;
    s[t] = v;
    __syncthreads();
    for (int off = 1; off < 512; off <<= 1) {
        int add = (t >= off) ? s[t - off] : 0;
        __syncthreads();
        s[t] += add;
        __syncthreads();
    }
    if (t < nb) boff[t] = s[t] - v;
}

__global__ void add_offsets_kernel(int* __restrict__ rowptr, int* __restrict__ cursor,
                                   const int* __restrict__ boff, int N, int E) {
    int i = blockIdx.x * blockDim.x + threadIdx.x;
    if (i < N) {
        int v = rowptr[i] + boff[i >> 8];
        rowptr[i] = v;
        cursor[i] = v;
    }
    if (i == 0) rowptr[N] = E;
}

// ---------- edge placement: CSR by destination, index only ----------

__global__ void place_kernel(const int* __restrict__ row, const int* __restrict__ col,
                             int* __restrict__ cursor, int* __restrict__ eidx, int E) {
    int e = blockIdx.x * blockDim.x + threadIdx.x;
    if (e < E) {
        int c = col[e];
        int pos = atomicAdd(&cursor[c], 1);
        eidx[pos] = row[e];
    }
}

// ---------- out = mf[0] * x ; hx = fp16(dinv[n] * x) in CHUNKED layout ----------

__global__ void init_out_kernel(const float4* __restrict__ x, const float* __restrict__ mf,
                                const float* __restrict__ dinv,
                                float4* __restrict__ out, __half* __restrict__ hx,
                                int N, long n8) {
    long i = (long)blockIdx.x * blockDim.x + threadIdx.x;
    if (i < n8) {
        float w = mf[0];
        float4 a = x[2 * i];
        float4 b = x[2 * i + 1];
        out[2 * i]     = make_float4(w * a.x, w * a.y, w * a.z, w * a.w);
        out[2 * i + 1] = make_float4(w * b.x, w * b.y, w * b.z, w * b.w);
        long n  = i >> 4;            // node (16 threads per node)
        int  f0 = (int)(i & 15) * 8; // first feature
        float dv = dinv[n];
        __half2 h[4];
        h[0] = __floats2half2_rn(dv * a.x, dv * a.y);
        h[1] = __floats2half2_rn(dv * a.z, dv * a.w);
        h[2] = __floats2half2_rn(dv * b.x, dv * b.y);
        h[3] = __floats2half2_rn(dv * b.z, dv * b.w);
        long haddr = ((long)(f0 >> 4) * N + n) * CF + (f0 & 8);
        *(f4*)(hx + haddr) = *(const f4*)h;
    }
}

// ---------- fused gather prop: feature-chunked, XCD-pinned, LDS-staged eidx ----------
// chunk c = blockIdx.x & 7 -> XCD c: gathers hit this XCD's L2-resident 3.2MB
// shadow chunk (written cacheable by the same XCD last pass).
// The block's 128 dsts own a CONTIGUOUS CSR edge window (~4096 ints). It is
// staged into LDS with coalesced fully-utilized nt loads (each 64B line read
// exactly once, no L2 retention) -> the index stream can no longer evict the
// chunk (round-4 failure) and no longer suffers nt line-amplification
// (round-5 failure). Hot loop: LDS idx read + 1KB wave gather + FMAs.
// Wave = 32 consecutive dsts x 2 feature-lanes; no cross-lane reduction.

__global__ __launch_bounds__(256) void gather_prop_kernel(
        const int* __restrict__ eidx, const int* __restrict__ rowptr,
        const float* __restrict__ dinv,
        const __half* __restrict__ src, const float* __restrict__ prev2,
        float* __restrict__ tgt, __half* __restrict__ tgth, float* __restrict__ out,
        const float* __restrict__ mf, const float* __restrict__ lap,
        int i_coef, float scale, float beta, int N) {
    __shared__ int s_idx[TILE_E];

    const int c    = blockIdx.x & 7;           // chunk -> XCD
    const int wave = threadIdx.x >> 6;
    const int lane = threadIdx.x & 63;
    const int dloc = lane >> 1;                // dst within wave 0..31
    const int fg   = lane & 1;                 // feature half: 8 fp16 = 16B
    const long cN  = (long)c * N;

    const int D0   = (blockIdx.x >> 3) * DPB;
    const int Dend = min(D0 + DPB, N);
    const int wbeg = rowptr[D0];
    const int wend = rowptr[Dend];

    int d = D0 + wave * 32 + dloc;
    bool valid = d < N;
    int begin = 0, end = 0;
    if (valid) {
        begin = rowptr[d];
        end   = rowptr[d + 1];
    }

    float acc[8];
    #pragma unroll
    for (int j = 0; j < 8; ++j) acc[j] = 0.f;

    const __half* srcc = src + (cN << 4) + (fg << 3);

    for (int tbeg = wbeg; tbeg < wend; tbeg += TILE_E) {
        int tend = min(tbeg + TILE_E, wend);
        __syncthreads();   // protect LDS before overwrite (no-op cost on 1st tile)
        for (int t = tbeg + threadIdx.x; t < tend; t += 256)
            s_idx[t - tbeg] = __builtin_nontemporal_load(eidx + t);
        __syncthreads();

        int lo = max(begin, tbeg);
        int hi = min(end, tend);
        int nit = max(0, hi - lo);
        int base = lo - tbeg;

        int maxit = nit;
        #pragma unroll
        for (int m = 2; m <= 32; m <<= 1)
            maxit = max(maxit, __shfl_xor(maxit, m, 64));

        #pragma unroll 4
        for (int k = 0; k < maxit; ++k) {
            int idx = 0;
            float wsel = 0.f;
            if (k < nit) {
                idx = s_idx[base + k];
                wsel = 1.f;
            }
            f4 raw = *(const f4*)(srcc + ((long)idx << 4));
            const __half2* h = (const __half2*)&raw;
            float2 f0 = __half22float2(h[0]);
            float2 f1 = __half22float2(h[1]);
            float2 f2 = __half22float2(h[2]);
            float2 f3 = __half22float2(h[3]);
            acc[0] += wsel * f0.x; acc[1] += wsel * f0.y;
            acc[2] += wsel * f1.x; acc[3] += wsel * f1.y;
            acc[4] += wsel * f2.x; acc[5] += wsel * f2.y;
            acc[6] += wsel * f3.x; acc[7] += wsel * f3.y;
        }
    }

    if (!valid) return;

    float dv   = __builtin_nontemporal_load(dinv + d);
    float sdv  = scale * dv;
    float coef = mf[i_coef] * lap[i_coef - 1];
    long  o    = ((long)d << 7) + (c << 4) + (fg << 3);  // fp32 linear elem offset

    float r[8];
    if (beta != 0.f) {
        f4 p0 = __builtin_nontemporal_load((const f4*)(prev2 + o));
        f4 p1 = __builtin_nontemporal_load((const f4*)(prev2 + o) + 1);
        r[0] = sdv * acc[0] + beta * p0.x;
        r[1] = sdv * acc[1] + beta * p0.y;
        r[2] = sdv * acc[2] + beta * p0.z;
        r[3] = sdv * acc[3] + beta * p0.w;
        r[4] = sdv * acc[4] + beta * p1.x;
        r[5] = sdv * acc[5] + beta * p1.y;
        r[6] = sdv * acc[6] + beta * p1.z;
        r[7] = sdv * acc[7] + beta * p1.w;
    } else {
        #pragma unroll
        for (int j = 0; j < 8; ++j) r[j] = sdv * acc[j];
    }
    f4 t0 = {r[0], r[1], r[2], r[3]};
    f4 t1 = {r[4], r[5], r[6], r[7]};
    __builtin_nontemporal_store(t0, (f4*)(tgt + o));
    __builtin_nontemporal_store(t1, (f4*)(tgt + o) + 1);
    if (tgth) {
        // chunked dinv-scaled shadow: cacheable -> stays in this XCD's L2
        __half2 hh[4];
        hh[0] = __floats2half2_rn(dv * r[0], dv * r[1]);
        hh[1] = __floats2half2_rn(dv * r[2], dv * r[3]);
        hh[2] = __floats2half2_rn(dv * r[4], dv * r[5]);
        hh[3] = __floats2half2_rn(dv * r[6], dv * r[7]);
        *(f4*)(tgth + ((cN + d) << 4) + (fg << 3)) = *(const f4*)hh;
    }
    f4 o0 = __builtin_nontemporal_load((const f4*)(out + o));
    f4 o1 = __builtin_nontemporal_load((const f4*)(out + o) + 1);
    o0.x += coef * r[0]; o0.y += coef * r[1]; o0.z += coef * r[2]; o0.w += coef * r[3];
    o1.x += coef * r[4]; o1.y += coef * r[5]; o1.z += coef * r[6]; o1.w += coef * r[7];
    __builtin_nontemporal_store(o0, (f4*)(out + o));
    __builtin_nontemporal_store(o1, (f4*)(out + o) + 1);
}

extern "C" void kernel_launch(void* const* d_in, const int* in_sizes, int n_in,
                              void* d_out, int out_size, void* d_ws, size_t ws_size,
                              hipStream_t stream) {
    const float* x   = (const float*)d_in[0];
    const float* mf  = (const float*)d_in[1];
    const float* lap = (const float*)d_in[2];
    const int*   ei  = (const int*)d_in[3];
    float* out = (float*)d_out;

    const int  K  = in_sizes[1] - 1;          // 10
    const long NF = (long)in_sizes[0];        // N*F
    const int  N  = (int)(NF / FDIM);         // 100000
    const int  E  = in_sizes[3] / 2;          // 3200000
    const int* row = ei;
    const int* col = ei + E;

    // workspace layout (~170 MB)
    char* wp = (char*)d_ws;
    float*  bufA   = (float*)wp;  wp += NF * sizeof(float);
    float*  bufB   = (float*)wp;  wp += NF * sizeof(float);
    __half* hbufA  = (__half*)wp; wp += NF * sizeof(__half);
    __half* hbufB  = (__half*)wp; wp += NF * sizeof(__half);
    int*    eidx   = (int*)wp;    wp += (size_t)E * sizeof(int);
    int*    rowptr = (int*)wp;    wp += (size_t)(N + 1) * sizeof(int);
    int*    cursor = (int*)wp;    wp += (size_t)N * sizeof(int);
    int*    deg    = (int*)wp;    wp += (size_t)N * sizeof(int);
    float*  dinv   = (float*)wp;  wp += (size_t)N * sizeof(float);
    int*    bsum   = (int*)wp;    wp += 512 * sizeof(int);
    int*    boff   = (int*)wp;    wp += 512 * sizeof(int);

    const int BT = 256;
    const long n8 = NF / 8;
    const int n8_blocks = (int)((n8 + BT - 1) / BT);
    const int e_blocks  = (E + BT - 1) / BT;
    const int n_blocks  = (N + BT - 1) / BT;

    // CSR build
    hipMemsetAsync(deg, 0, (size_t)N * sizeof(int), stream);
    degree_kernel<<<e_blocks, BT, 0, stream>>>(col, deg, E);
    dinv_kernel<<<n_blocks, BT, 0, stream>>>(deg, dinv, N);
    scan_blocks_kernel<<<n_blocks, BT, 0, stream>>>(deg, rowptr, bsum, N);
    scan_bsums_kernel<<<1, 512, 0, stream>>>(bsum, boff, n_blocks);
    add_offsets_kernel<<<n_blocks, BT, 0, stream>>>(rowptr, cursor, boff, N, E);
    place_kernel<<<e_blocks, BT, 0, stream>>>(row, col, cursor, eidx, E);

    // out = mf0 * x ; hbufB = fp16(dinv*x) chunked  (hbufB free until i=2)
    init_out_kernel<<<n8_blocks, BT, 0, stream>>>((const float4*)x, mf, dinv,
                                                  (float4*)out, hbufB, N, n8);

    // grid: 8 chunks x (DPB dsts per block); chunk = bid & 7 -> XCD pin
    const int g_blocks = 8 * ((N + DPB - 1) / DPB);

    // P1 = prop(x) -> bufA (+hbufA) ; out += c1*P1   (gathers chunked fp16 dinv*x)
    gather_prop_kernel<<<g_blocks, BT, 0, stream>>>(eidx, rowptr, dinv, hbufB, x,
                                                    bufA, hbufA, out, mf, lap,
                                                    1, 1.0f, 0.0f, N);
    // P_i = 2*prop(P_{i-1}) - P_{i-2} ; out += c_i*P_i   (gathers fp16 shadow)
    for (int i = 2; i <= K; ++i) {
        const __half* srch  = (i % 2 == 0) ? hbufA : hbufB;  // fp16(dinv*P_{i-1})
        float*        tgt   = (i % 2 == 0) ? bufB : bufA;    // P_i (overwrites P_{i-2})
        __half*       tgth  = (i % 2 == 0) ? hbufB : hbufA;
        const float*  prev2 = (i == 2) ? x : (const float*)tgt;
        if (i == K) tgth = nullptr;  // last shadow never gathered
        gather_prop_kernel<<<g_blocks, BT, 0, stream>>>(eidx, rowptr, dinv, srch, prev2,
                                                        tgt, tgth, out, mf, lap,
                                                        i, 2.0f, -1.0f, N);
    }
}

// Round 7
// 1901.978 us; speedup vs baseline: 3.5840x; 1.5209x over previous
//
#include <hip/hip_runtime.h>
#include <hip/hip_bf16.h>
#include <hip/hip_fp16.h>

#define FDIM 128

typedef float f4 __attribute__((ext_vector_type(4)));

// ---------- degree / dinv ----------

__global__ void degree_kernel(const int* __restrict__ col, int* __restrict__ deg, int E) {
    int e = blockIdx.x * blockDim.x + threadIdx.x;
    if (e < E) atomicAdd(&deg[col[e]], 1);
}

__global__ void dinv_kernel(const int* __restrict__ deg, float* __restrict__ dinv, int N) {
    int i = blockIdx.x * blockDim.x + threadIdx.x;
    if (i < N) {
        int d = deg[i];
        dinv[i] = (d > 0) ? rsqrtf((float)d) : 0.0f;
    }
}

// ---------- exclusive scan of deg -> rowptr ----------

__global__ void scan_blocks_kernel(const int* __restrict__ deg, int* __restrict__ rowptr,
                                   int* __restrict__ bsum, int N) {
    __shared__ int s[256];
    int t = threadIdx.x;
    int i = blockIdx.x * 256 + t;
    int v = (i < N) ? deg[i] : 0;
    s[t] = v;
    __syncthreads();
    for (int off = 1; off < 256; off <<= 1) {
        int add = (t >= off) ? s[t - off] : 0;
        __syncthreads();
        s[t] += add;
        __syncthreads();
    }
    if (i < N) rowptr[i] = s[t] - v;
    if (t == 255) bsum[blockIdx.x] = s[255];
}

__global__ void scan_bsums_kernel(int* __restrict__ bsum, int* __restrict__ boff, int nb) {
    __shared__ int s[512];
    int t = threadIdx.x;
    int v = (t < nb) ? bsum[t] : 0;
    s[t] = v;
    __syncthreads();
    for (int off = 1; off < 512; off <<= 1) {
        int add = (t >= off) ? s[t - off] : 0;
        __syncthreads();
        s[t] += add;
        __syncthreads();
    }
    if (t < nb) boff[t] = s[t] - v;
}

__global__ void add_offsets_kernel(int* __restrict__ rowptr, int* __restrict__ cursor,
                                   const int* __restrict__ boff, int N, int E) {
    int i = blockIdx.x * blockDim.x + threadIdx.x;
    if (i < N) {
        int v = rowptr[i] + boff[i >> 8];
        rowptr[i] = v;
        cursor[i] = v;
    }
    if (i == 0) rowptr[N] = E;
}

// ---------- two-phase octant edge placement ----------
// Phase A: stream edges into 8 dst-octant buffers (append order -> coalesced
// writes). Phase B: blocks pinned to XCD (bid&7 = octant) scatter into the
// octant's CSR slice (~3.2MB of edata) which FITS that XCD's L2 -> dirty
// lines collect all ~16 sharers before eviction (single-phase place evicted
// each 64B line per 4B write: 195MB @ 0.73 TB/s = 267us).

__global__ void octant_init_kernel(const int* __restrict__ rowptr,
                                   int* __restrict__ gcur, int N) {
    int o = threadIdx.x;
    if (o < 8) gcur[o] = rowptr[(int)(((long)o * N + 7) / 8)];
}

__global__ __launch_bounds__(256) void binA_kernel(
        const int* __restrict__ row, const int* __restrict__ col,
        unsigned long long* __restrict__ obuf, int* __restrict__ gcur,
        int N, int E) {
    __shared__ int scnt[8];
    __shared__ int sbase[8];
    int t = threadIdx.x;
    if (t < 8) scnt[t] = 0;
    __syncthreads();
    int e = blockIdx.x * 256 + t;
    int o = 0, rank = 0;
    unsigned long long pay = 0;
    bool v = e < E;
    if (v) {
        int r = row[e], c = col[e];
        o = (int)(((long)c * 8) / N);
        pay = ((unsigned long long)(unsigned)c << 32) | (unsigned)r;
        rank = atomicAdd(&scnt[o], 1);
    }
    __syncthreads();
    if (t < 8) sbase[t] = atomicAdd(&gcur[t], scnt[t]);
    __syncthreads();
    if (v) obuf[sbase[o] + rank] = pay;
}

__global__ __launch_bounds__(256) void binB_kernel(
        const unsigned long long* __restrict__ obuf, const int* __restrict__ gend,
        const int* __restrict__ rowptr, const float* __restrict__ dinv,
        int* __restrict__ cursor, float2* __restrict__ edata, int N, int M) {
    int o = blockIdx.x & 7;      // octant -> XCD pin
    int j = blockIdx.x >> 3;
    int sb = rowptr[(int)(((long)o * N + 7) / 8)];
    int en = gend[o];
    for (int p = sb + j * 256 + threadIdx.x; p < en; p += M * 256) {
        unsigned long long pay = obuf[p];
        int r = (int)(pay & 0xffffffffu);
        int c = (int)(pay >> 32);
        float w = dinv[r] * dinv[c];
        int pos = atomicAdd(&cursor[c], 1);
        edata[pos] = make_float2(__int_as_float(r), w);
    }
}

// ---------- out = mf[0] * x ; hx = fp16(x), flat layout ----------

__global__ void init_out_kernel(const float4* __restrict__ x, const float* __restrict__ mf,
                                float4* __restrict__ out, float4* __restrict__ hx, long n8) {
    long i = (long)blockIdx.x * blockDim.x + threadIdx.x;
    if (i < n8) {
        float w = mf[0];
        float4 a = x[2 * i];
        float4 b = x[2 * i + 1];
        out[2 * i]     = make_float4(w * a.x, w * a.y, w * a.z, w * a.w);
        out[2 * i + 1] = make_float4(w * b.x, w * b.y, w * b.z, w * b.w);
        __half2 h[4];
        h[0] = __floats2half2_rn(a.x, a.y);
        h[1] = __floats2half2_rn(a.z, a.w);
        h[2] = __floats2half2_rn(b.x, b.y);
        h[3] = __floats2half2_rn(b.z, b.w);
        hx[i] = *(const float4*)h;
    }
}

// ---------- fused gather prop, 4 edges per wave (round-2 proven form) ----------
// wave = one dst node. lane = 16*g + fl : group g (0..3) processes edge e0+g,
// feature-lane fl (0..15) holds features [8*fl, 8*fl+8). One 1KB gather per
// iteration (4 x 256B fully-utilized rows); runs at the ~6.3TB/s fill ceiling.

__global__ __launch_bounds__(256) void gather_prop_kernel(
        const float2* __restrict__ edata, const int* __restrict__ rowptr,
        const __half* __restrict__ src, const float* __restrict__ prev2,
        float* __restrict__ tgt, __half* __restrict__ tgth, float* __restrict__ out,
        const float* __restrict__ mf, const float* __restrict__ lap,
        int i_coef, float scale, float beta, int N) {
    int wid = blockIdx.x * 4 + (threadIdx.x >> 6);
    if (wid >= N) return;
    int lane = threadIdx.x & 63;
    int g  = lane >> 4;        // edge group within wave
    int fl = lane & 15;        // feature lane
    int feoff = fl << 3;       // element offset within a 128-elem row

    int begin = rowptr[wid];
    int end   = rowptr[wid + 1];

    float acc[8];
    #pragma unroll
    for (int j = 0; j < 8; ++j) acc[j] = 0.f;

    #pragma unroll 4
    for (int e0 = begin; e0 < end; e0 += 4) {
        int e = e0 + g;
        float w = 0.f;
        int idx = 0;
        if (e < end) {
            float2 ed = edata[e];
            idx = __float_as_int(ed.x);
            w = ed.y;
        }
        f4 raw = *(const f4*)(src + ((long)idx << 7) + feoff);
        const __half2* h = (const __half2*)&raw;
        float2 f0 = __half22float2(h[0]);
        float2 f1 = __half22float2(h[1]);
        float2 f2 = __half22float2(h[2]);
        float2 f3 = __half22float2(h[3]);
        acc[0] += w * f0.x; acc[1] += w * f0.y;
        acc[2] += w * f1.x; acc[3] += w * f1.y;
        acc[4] += w * f2.x; acc[5] += w * f2.y;
        acc[6] += w * f3.x; acc[7] += w * f3.y;
    }

    // reduce the 4 edge groups (lanes fl, fl+16, fl+32, fl+48)
    #pragma unroll
    for (int j = 0; j < 8; ++j) {
        acc[j] += __shfl_xor(acc[j], 16, 64);
        acc[j] += __shfl_xor(acc[j], 32, 64);
    }

    if (g == 0) {
        float coef = mf[i_coef] * lap[i_coef - 1];
        long o = ((long)wid << 7) + feoff;   // element offset
        float r[8];
        if (beta != 0.f) {
            f4 p0 = __builtin_nontemporal_load((const f4*)(prev2 + o));
            f4 p1 = __builtin_nontemporal_load((const f4*)(prev2 + o) + 1);
            r[0] = scale * acc[0] + beta * p0.x;
            r[1] = scale * acc[1] + beta * p0.y;
            r[2] = scale * acc[2] + beta * p0.z;
            r[3] = scale * acc[3] + beta * p0.w;
            r[4] = scale * acc[4] + beta * p1.x;
            r[5] = scale * acc[5] + beta * p1.y;
            r[6] = scale * acc[6] + beta * p1.z;
            r[7] = scale * acc[7] + beta * p1.w;
        } else {
            #pragma unroll
            for (int j = 0; j < 8; ++j) r[j] = scale * acc[j];
        }
        f4 t0 = {r[0], r[1], r[2], r[3]};
        f4 t1 = {r[4], r[5], r[6], r[7]};
        __builtin_nontemporal_store(t0, (f4*)(tgt + o));
        __builtin_nontemporal_store(t1, (f4*)(tgt + o) + 1);
        if (tgth) {
            __half2 hh[4];
            hh[0] = __floats2half2_rn(r[0], r[1]);
            hh[1] = __floats2half2_rn(r[2], r[3]);
            hh[2] = __floats2half2_rn(r[4], r[5]);
            hh[3] = __floats2half2_rn(r[6], r[7]);
            __builtin_nontemporal_store(*(const f4*)hh, (f4*)(tgth + o));
        }
        f4 o0 = __builtin_nontemporal_load((const f4*)(out + o));
        f4 o1 = __builtin_nontemporal_load((const f4*)(out + o) + 1);
        o0.x += coef * r[0]; o0.y += coef * r[1]; o0.z += coef * r[2]; o0.w += coef * r[3];
        o1.x += coef * r[4]; o1.y += coef * r[5]; o1.z += coef * r[6]; o1.w += coef * r[7];
        __builtin_nontemporal_store(o0, (f4*)(out + o));
        __builtin_nontemporal_store(o1, (f4*)(out + o) + 1);
    }
}

extern "C" void kernel_launch(void* const* d_in, const int* in_sizes, int n_in,
                              void* d_out, int out_size, void* d_ws, size_t ws_size,
                              hipStream_t stream) {
    const float* x   = (const float*)d_in[0];
    const float* mf  = (const float*)d_in[1];
    const float* lap = (const float*)d_in[2];
    const int*   ei  = (const int*)d_in[3];
    float* out = (float*)d_out;

    const int  K  = in_sizes[1] - 1;          // 10
    const long NF = (long)in_sizes[0];        // N*F
    const int  N  = (int)(NF / FDIM);         // 100000
    const int  E  = in_sizes[3] / 2;          // 3200000
    const int* row = ei;
    const int* col = ei + E;

    // workspace layout (~180 MB)
    char* wp = (char*)d_ws;
    float*  bufA   = (float*)wp;  wp += NF * sizeof(float);
    float*  bufB   = (float*)wp;  wp += NF * sizeof(float);
    __half* hbufA  = (__half*)wp; wp += NF * sizeof(__half);
    __half* hbufB  = (__half*)wp; wp += NF * sizeof(__half);
    float2* edata  = (float2*)wp; wp += (size_t)E * sizeof(float2);
    int*    rowptr = (int*)wp;    wp += (size_t)(N + 1) * sizeof(int);
    int*    cursor = (int*)wp;    wp += (size_t)N * sizeof(int);
    int*    deg    = (int*)wp;    wp += (size_t)N * sizeof(int);
    float*  dinv   = (float*)wp;  wp += (size_t)N * sizeof(float);
    int*    bsum   = (int*)wp;    wp += 512 * sizeof(int);
    int*    boff   = (int*)wp;    wp += 512 * sizeof(int);
    int*    gcur   = (int*)wp;    wp += 8 * sizeof(int);

    // octant append buffer aliases bufA (only written by gathers, which run later)
    unsigned long long* obuf = (unsigned long long*)bufA;

    const int BT = 256;
    const long n8 = NF / 8;
    const int n8_blocks = (int)((n8 + BT - 1) / BT);
    const int e_blocks  = (E + BT - 1) / BT;
    const int n_blocks  = (N + BT - 1) / BT;

    // CSR build
    hipMemsetAsync(deg, 0, (size_t)N * sizeof(int), stream);
    degree_kernel<<<e_blocks, BT, 0, stream>>>(col, deg, E);
    dinv_kernel<<<n_blocks, BT, 0, stream>>>(deg, dinv, N);
    scan_blocks_kernel<<<n_blocks, BT, 0, stream>>>(deg, rowptr, bsum, N);
    scan_bsums_kernel<<<1, 512, 0, stream>>>(bsum, boff, n_blocks);
    add_offsets_kernel<<<n_blocks, BT, 0, stream>>>(rowptr, cursor, boff, N, E);
    octant_init_kernel<<<1, 8, 0, stream>>>(rowptr, gcur, N);
    binA_kernel<<<e_blocks, BT, 0, stream>>>(row, col, obuf, gcur, N, E);
    const int M = 256;   // blocks per octant in phase B
    binB_kernel<<<8 * M, BT, 0, stream>>>(obuf, gcur, rowptr, dinv, cursor, edata, N, M);

    // out = mf0 * x ; hbufB = fp16(x) flat  (hbufB free until i=2 writes it)
    init_out_kernel<<<n8_blocks, BT, 0, stream>>>((const float4*)x, mf, (float4*)out,
                                                  (float4*)hbufB, n8);

    const int g_blocks = (N + 3) / 4;

    // P1 = prop(x) -> bufA (+hbufA) ; out += c1*P1   (gathers fp16 copy of x)
    gather_prop_kernel<<<g_blocks, BT, 0, stream>>>(edata, rowptr, hbufB, x,
                                                    bufA, hbufA, out, mf, lap,
                                                    1, 1.0f, 0.0f, N);
    // P_i = 2*prop(P_{i-1}) - P_{i-2} ; out += c_i*P_i   (gathers fp16 shadow)
    for (int i = 2; i <= K; ++i) {
        const __half* srch  = (i % 2 == 0) ? hbufA : hbufB;  // fp16(P_{i-1})
        float*        tgt   = (i % 2 == 0) ? bufB : bufA;    // P_i (overwrites P_{i-2})
        __half*       tgth  = (i % 2 == 0) ? hbufB : hbufA;
        const float*  prev2 = (i == 2) ? x : (const float*)tgt;
        if (i == K) tgth = nullptr;  // last shadow never gathered
        gather_prop_kernel<<<g_blocks, BT, 0, stream>>>(edata, rowptr, srch, prev2,
                                                        tgt, tgth, out, mf, lap,
                                                        i, 2.0f, -1.0f, N);
    }
}